// Round 15
// baseline (118.793 us; speedup 1.0000x reference)
//
#include <hip/hip_runtime.h>

// Problem constants
#define BDIM   16
#define PDIM   12
#define TDIM   4096
#define WINW   41
#define PADW   20
#define DDIM   492      // P*WIN
#define KCODES 1024

// fp8 32x32x16 MFMA geometry. Tiles laid out with 32 K-steps (16 KiB) but
// step 31 covers k in [496,512) >= DDIM=492 -> all zeros -> skip it.
#define KS32   32                   // K-steps in the tile LAYOUT
#define KSU    31                   // K-steps actually USED
#define NT32   32                   // code tiles of 32 -> 1024 codes
#define NT32_BYTES (KS32 * 64 * 8)  // 16 KiB per code tile

// R5-R14 lessons: (1) resident waves/CU == ONE block's waves (2 blocks/CU
// never co-schedule: 11% occ both tries); (2) the backend pins VGPR to
// 512/(waves-per-SIMD target) and spills if the live set exceeds it; (3) at
// 2 waves/SIMD, phase-locked waves leave MfmaUtil stuck at ~27%.
// => 1024-thr/16-wave blocks: 4 waves/SIMD (cap 128 >= our ~115 live set),
// grid kept at 256 (1 block/CU) by splitting the codebook into 2 halves.
#define WAVES      16                // 1024-thread blocks
#define ROWS_WAVE  32
#define BMROWS     (WAVES * ROWS_WAVE)   // 512 rows per block
#define MROWS      (BDIM * TDIM)         // 65536
#define NRB        (MROWS / BMROWS)      // 128 row-blocks
#define NHALF      2                     // x2 code halves -> grid 256
#define NT_HALF    (NT32 / NHALF)        // 16 tiles per sweep
#define NSTEP      (NT_HALF / 2)         // 8 two-tile steps per sweep

#define NBUF   6                    // 96 KiB staging LDS ring (3 steps)

typedef __attribute__((ext_vector_type(16))) float f32x16;

// two f32 pairs -> 4 e4m3 bytes (RNE, saturating) via v_cvt_pk_fp8_f32
__device__ __forceinline__ unsigned int pack4_fp8(float a, float b, float c, float d) {
    int v = 0;
    v = __builtin_amdgcn_cvt_pk_fp8_f32(a, b, v, false);  // bytes 0,1
    v = __builtin_amdgcn_cvt_pk_fp8_f32(c, d, v, true);   // bytes 2,3
    return (unsigned int)v;
}

// Pre-format codebook into fp8 B-fragments for mfma_f32_32x32x16_fp8_fp8.
// frag idx = (nt*KS32 + ks)*64 + lane, 8 bytes each:
//   B[k][n], n = nt*32 + (lane&31), k = ks*16 + (lane>>5)*8 + j  (byte j)
__global__ __launch_bounds__(256) void prep_bfrag_k(const float* __restrict__ cb,
                                                    unsigned long long* __restrict__ bfrag) {
    int idx  = blockIdx.x * 256 + threadIdx.x;   // 0..65535
    int lane = idx & 63;
    int ks   = (idx >> 6) & (KS32 - 1);
    int nt   = idx >> 11;
    int n    = nt * 32 + (lane & 31);
    int hi2  = lane >> 5;
    float v[8];
#pragma unroll
    for (int j = 0; j < 8; ++j) {
        int k = ks * 16 + hi2 * 8 + j;
        v[j] = (k < DDIM) ? cb[n * DDIM + k] : 0.f;
    }
    unsigned int lo = pack4_fp8(v[0], v[1], v[2], v[3]);
    unsigned int hi = pack4_fp8(v[4], v[5], v[6], v[7]);
    bfrag[idx] = ((unsigned long long)hi << 32) | lo;
}

// Exact fp32 code norms.
__global__ __launch_bounds__(64) void prep_cnorm_k(const float* __restrict__ cb,
                                                   float* __restrict__ cnorm) {
    int n = blockIdx.x;
    int lane = threadIdx.x;
    float s = 0.f;
    for (int d = lane; d < DDIM; d += 64) { float c = cb[n * DDIM + d]; s += c * c; }
#pragma unroll
    for (int m = 1; m < 64; m <<= 1) s += __shfl_xor(s, m, 64);
    if (lane == 0) cnorm[n] = s;
}

// Exact sum of ||f||^2 over all rows via window multiplicity:
// mult(tt) = 41 - max(0,20-tt) - max(0,tt-4075).
__global__ __launch_bounds__(256) void xsq_k(const float* __restrict__ x,
                                             float* __restrict__ xsq_part) {
    float s = 0.f;
    for (int i = blockIdx.x * 256 + threadIdx.x; i < BDIM * PDIM * TDIM; i += 256 * 256) {
        int tt = i & (TDIM - 1);
        int mult = WINW - max(0, PADW - tt) - max(0, tt - (TDIM - 1 - PADW));
        float v = x[i];
        s += (float)mult * v * v;
    }
#pragma unroll
    for (int m = 1; m < 64; m <<= 1) s += __shfl_xor(s, m, 64);
    __shared__ float sm[4];
    if ((threadIdx.x & 63) == 0) sm[threadIdx.x >> 6] = s;
    __syncthreads();
    if (threadIdx.x == 0) xsq_part[blockIdx.x] = sm[0] + sm[1] + sm[2] + sm[3];
}

// Stage one 16 KiB code tile into LDS. With 16 waves: exactly ONE
// global_load_lds (16 B/lane) per wave per tile.
__device__ __forceinline__ void stage_nt(const unsigned char* __restrict__ g_half,
                                         unsigned char* dst, int nt, int wave, int lane) {
    const unsigned char* g = g_half + (size_t)nt * NT32_BYTES;
    int off = wave * 1024;
    __builtin_amdgcn_global_load_lds(
        (const __attribute__((address_space(1))) unsigned int*)(g + off + lane * 16),
        (__attribute__((address_space(3))) unsigned int*)(dst + off),
        16, 0, 0);
}

// Main sweep: grid (128 row-blocks x 2 code-halves) x 16 waves x 32 rows.
// fp8 A-slab in registers; this half's 16 code tiles streamed through a
// 6-buffer LDS ring in 2-tile steps (8 barriers/sweep), counted vmcnt
// (vmcnt(2) steady / vmcnt(0) tail) + raw s_barrier. Single acc chain
// (live ~115 regs <= 128 cap at 4 waves/SIMD -> no spill).
// Per-row maxes -> rowmax[half][row]; halves combined by reduce kernels.
__global__ __launch_bounds__(1024)
void vq_main_k(const float* __restrict__ x,
               const unsigned char* __restrict__ bfrag,
               const float* __restrict__ cnorm,
               float* __restrict__ rowmax) {
    __shared__ __align__(16) unsigned char smem[NBUF][NT32_BYTES];   // 96 KiB
    __shared__ float sb_lds[KCODES / NHALF];                         // 2 KiB

    const int lane = threadIdx.x & 63;
    const int wave = threadIdx.x >> 6;
    const int col  = lane & 31;     // B/D column within tile
    const int hi2  = lane >> 5;
    const int by   = blockIdx.y;
    const int rowbase = blockIdx.x * BMROWS + wave * ROWS_WAVE;
    const unsigned char* g_half = bfrag + (size_t)by * NT_HALF * NT32_BYTES;

    // Stage steps 0,1 (tiles 0..3); latency covered by sb-table + A-build.
#pragma unroll
    for (int t = 0; t < 4; ++t)
        stage_nt(g_half, smem[t], t, wave, lane);

    // Bias table for this half: sb_lds[i] = -0.5*||c_(by*512+i)||^2
    if (threadIdx.x < KCODES / NHALF)
        sb_lds[threadIdx.x] = -0.5f * cnorm[by * (KCODES / NHALF) + threadIdx.x];

    // ---- Build fp8 A-slab: row = rowbase + col, k = ks*16 + hi2*8 + j ----
    long afr[KSU];
    {
        int row = rowbase + col;
        int b = row >> 12;
        int t = row & (TDIM - 1);
        const float* xb = x + (size_t)b * (PDIM * TDIM);
#pragma unroll
        for (int ks = 0; ks < KSU; ++ks) {
            float v[8];
#pragma unroll
            for (int j = 0; j < 8; ++j) {
                int d = ks * 16 + hi2 * 8 + j;
                float f = 0.f;
                if (d < DDIM) {
                    int p  = d / WINW;
                    int w  = d - p * WINW;
                    int tt = t + w - PADW;
                    if (tt >= 0 && tt < TDIM) f = xb[p * TDIM + tt];
                }
                v[j] = f;
            }
            unsigned int lo = pack4_fp8(v[0], v[1], v[2], v[3]);
            unsigned int hi = pack4_fp8(v[4], v[5], v[6], v[7]);
            afr[ks] = (long)(((unsigned long long)hi << 32) | lo);
        }
    }

    f32x16 bs;
#pragma unroll
    for (int r = 0; r < 16; ++r) bs[r] = -3.0e38f;

    // Full drain at pipeline entry (steps 0,1 resident; sb_lds visible).
    __syncthreads();

    for (int s = 0; s < NSTEP; ++s) {
        if (s > 0) {
            // Retire stage-step(s); step s+1 (2 loads) may stay in flight.
            if (s < NSTEP - 1) asm volatile("s_waitcnt vmcnt(2)" ::: "memory");
            else               asm volatile("s_waitcnt vmcnt(0)" ::: "memory");
            __builtin_amdgcn_s_barrier();   // step s resident; step s-1 bufs free
            __builtin_amdgcn_sched_barrier(0);
        }
        // Prefetch step s+2 into the bufs freed at step s-1.
        if (s + 2 < NSTEP) {
            stage_nt(g_half, smem[(2 * s + 4) % NBUF], 2 * s + 4, wave, lane);
            stage_nt(g_half, smem[(2 * s + 5) % NBUF], 2 * s + 5, wave, lane);
        }

#pragma unroll
        for (int tl = 0; tl < 2; ++tl) {
            const int nt = 2 * s + tl;
            const long* bp = (const long*)(smem[nt % NBUF]) + lane;
            f32x16 acc;
#pragma unroll
            for (int r = 0; r < 16; ++r) acc[r] = 0.f;

            __builtin_amdgcn_s_setprio(1);
#pragma unroll
            for (int ks = 0; ks < KSU; ++ks) {
                long bq = bp[ks * 64];
                acc = __builtin_amdgcn_mfma_f32_32x32x16_fp8_fp8(afr[ks], bq, acc, 0, 0, 0);
            }
            __builtin_amdgcn_s_setprio(0);

            const float sb = sb_lds[nt * 32 + col];
#pragma unroll
            for (int r = 0; r < 16; ++r)
                bs[r] = fmaxf(bs[r], acc[r] + sb);
        }
    }

    // ---- Per-row max across the 32 col-lanes (masks<32 preserve hi2) ----
#pragma unroll
    for (int m = 1; m < 32; m <<= 1)
#pragma unroll
        for (int r = 0; r < 16; ++r)
            bs[r] = fmaxf(bs[r], __shfl_xor(bs[r], m, 64));

    // D rows: row = (r&3) + 8*(r>>2) + 4*hi2 within the 32-row slab. Both
    // halves use the identical mapping, so the cross-half fmax pairing and
    // the final sum are mapping-invariant.
    if (col == 0) {
        float* dst = rowmax + (size_t)by * MROWS + rowbase;
#pragma unroll
        for (int r = 0; r < 16; ++r)
            dst[(r & 3) + 8 * (r >> 2) + 4 * hi2] = bs[r];
    }
}

// Stage 1: 256 blocks x 256 rows: sum of fmax(rowmax0, rowmax1) per block.
__global__ __launch_bounds__(256) void reduce1_k(const float* __restrict__ rowmax,
                                                 float* __restrict__ bpart) {
    int r = blockIdx.x * 256 + threadIdx.x;
    float s = fmaxf(rowmax[r], rowmax[MROWS + r]);
#pragma unroll
    for (int m = 1; m < 64; m <<= 1) s += __shfl_xor(s, m, 64);
    __shared__ float sm[4];
    if ((threadIdx.x & 63) == 0) sm[threadIdx.x >> 6] = s;
    __syncthreads();
    if (threadIdx.x == 0) bpart[blockIdx.x] = sm[0] + sm[1] + sm[2] + sm[3];
}

// Stage 2: loss = 0.25 * (Sxx - 2*sum bpart) / (65536*492)
__global__ __launch_bounds__(256) void reduce2_k(const float* __restrict__ bpart,
                                                 const float* __restrict__ xsq_part,
                                                 float* __restrict__ out) {
    __shared__ double sm[256];
    int tid = threadIdx.x;
    sm[tid] = (double)bpart[tid];
    __syncthreads();
    for (int st = 128; st > 0; st >>= 1) {
        if (tid < st) sm[tid] += sm[tid + st];
        __syncthreads();
    }
    double S1 = sm[0];
    __syncthreads();
    sm[tid] = (double)xsq_part[tid];
    __syncthreads();
    for (int st = 128; st > 0; st >>= 1) {
        if (tid < st) sm[tid] += sm[tid + st];
        __syncthreads();
    }
    if (tid == 0)
        out[0] = (float)(0.25 * (sm[0] - 2.0 * S1) / ((double)MROWS * (double)DDIM));
}

extern "C" void kernel_launch(void* const* d_in, const int* in_sizes, int n_in,
                              void* d_out, int out_size, void* d_ws, size_t ws_size,
                              hipStream_t stream) {
    const float* x  = (const float*)d_in[0];   // (16,12,4096) f32
    const float* cb = (const float*)d_in[1];   // (1024,492) f32
    float* out = (float*)d_out;

    // workspace layout (~1.04 MiB)
    char* ws = (char*)d_ws;
    unsigned long long* bfrag = (unsigned long long*)ws;            // 512 KiB
    float* cnorm    = (float*)(ws + (512u << 10));                  // 4 KiB
    float* xsq_part = (float*)(ws + (512u << 10) + 4096);           // 1 KiB
    float* bpart    = (float*)(ws + (512u << 10) + 8192);           // 1 KiB
    float* rowmax   = (float*)(ws + (512u << 10) + 16384);          // 512 KiB

    prep_bfrag_k<<<256, 256, 0, stream>>>(cb, bfrag);
    prep_cnorm_k<<<KCODES, 64, 0, stream>>>(cb, cnorm);
    xsq_k<<<256, 256, 0, stream>>>(x, xsq_part);
    vq_main_k<<<dim3(NRB, NHALF), 1024, 0, stream>>>(x, (const unsigned char*)bfrag,
                                                     cnorm, rowmax);
    reduce1_k<<<256, 256, 0, stream>>>(rowmax, bpart);
    reduce2_k<<<1, 256, 0, stream>>>(bpart, xsq_part, out);
}